// Round 1
// baseline (21.907 us; speedup 1.0000x reference)
//
#include <hip/hip_runtime.h>

#define NF 8
#define DEG 4
#define NTERMS 495

// ---------------------------------------------------------------------------
// prep: w[t] = facs[t] * coefs[t]
// ---------------------------------------------------------------------------
__global__ void prep_w(const float* __restrict__ coefs,
                       const float* __restrict__ facs,
                       float* __restrict__ w) {
    int i = blockIdx.x * blockDim.x + threadIdx.x;
    if (i < NTERMS) w[i] = facs[i] * coefs[i];
}

// ---------------------------------------------------------------------------
// Compile-time enumeration of all exponent multi-indices with total degree
// <= DEG over NF variables, in the reference's lexicographic order
// (e0 slowest ... e7 fastest). Maintains a running prefix product; one
// multiply per tree node, one FMA per term. All indices constant-fold.
// Accumulator pair (a0,a1) is swapped at each branch step so consecutive
// terms alternate accumulators (breaks the serial FMA chain).
// ---------------------------------------------------------------------------
template<int F, int REM> struct Node;
template<int F, int REM, int E> struct Branch;

template<int F, int REM>
struct Node {
    static __device__ __forceinline__ void run(const float* xs,
                                               const float* __restrict__ w,
                                               int& t, float p,
                                               float& a0, float& a1) {
        Branch<F, REM, 0>::run(xs, w, t, p, a0, a1);
    }
};

// leaf: all 8 exponents assigned -> emit one term
template<int REM>
struct Node<NF, REM> {
    static __device__ __forceinline__ void run(const float* /*xs*/,
                                               const float* __restrict__ w,
                                               int& t, float p,
                                               float& a0, float& a1) {
        a0 = fmaf(w[t], p, a0);
        ++t;
    }
};

template<int F, int REM, int E>
struct Branch {
    static __device__ __forceinline__ void run(const float* xs,
                                               const float* __restrict__ w,
                                               int& t, float pf,
                                               float& a0, float& a1) {
        Node<F + 1, REM - E>::run(xs, w, t, pf, a0, a1);
        if constexpr (E < REM) {
            // next exponent for feature F: multiply running product by x[F],
            // swap accumulators for the sibling subtree
            Branch<F, REM, E + 1>::run(xs, w, t, pf * xs[F], a1, a0);
        }
    }
};

__global__ __launch_bounds__(256)
void maclaurin_eval(const float* __restrict__ x,
                    const float* __restrict__ w,
                    float* __restrict__ out, int n) {
    int b = blockIdx.x * blockDim.x + threadIdx.x;
    if (b >= n) return;

    const float4* xp = (const float4*)(x + (size_t)b * NF);
    float4 v0 = xp[0];
    float4 v1 = xp[1];
    float xs[NF];
    xs[0] = v0.x; xs[1] = v0.y; xs[2] = v0.z; xs[3] = v0.w;
    xs[4] = v1.x; xs[5] = v1.y; xs[6] = v1.z; xs[7] = v1.w;

    float a0 = 0.0f, a1 = 0.0f;
    int t = 0;
    Node<0, DEG>::run(xs, w, t, 1.0f, a0, a1);

    out[b] = a0 + a1;
}

// ---------------------------------------------------------------------------
// launch
// ---------------------------------------------------------------------------
extern "C" void kernel_launch(void* const* d_in, const int* in_sizes, int n_in,
                              void* d_out, int out_size, void* d_ws, size_t ws_size,
                              hipStream_t stream) {
    // inputs (setup_inputs order): x [B,8] f32, terms [495,8] f32,
    //                              coefs [1,495] f32, facs [495] f32
    const float* x     = (const float*)d_in[0];
    const float* coefs = (const float*)d_in[2];
    const float* facs  = (const float*)d_in[3];
    float* w   = (float*)d_ws;   // 495 floats of scratch
    float* out = (float*)d_out;

    int n = in_sizes[0] / NF;    // 65536

    prep_w<<<(NTERMS + 255) / 256, 256, 0, stream>>>(coefs, facs, w);
    maclaurin_eval<<<(n + 255) / 256, 256, 0, stream>>>(x, w, out, n);
}

// Round 2
// 11.109 us; speedup vs baseline: 1.9721x; 1.9721x over previous
//
#include <hip/hip_runtime.h>

#define NF 8
#define DEG 4
#define NTERMS 495

// ---------------------------------------------------------------------------
// Compile-time enumeration of all exponent multi-indices with total degree
// <= DEG over NF variables, in the reference's lexicographic order
// (e0 slowest ... e7 fastest). Running prefix product: one v_mul per internal
// tree node (1286 total), one v_fma per term (495). All indices constant-fold
// (single basic block after inlining -> LLVM merges consecutive LDS offsets
// into ds_read_b128). Accumulator pair swapped per branch step to break the
// serial FMA chain.
// ---------------------------------------------------------------------------
template<int F, int REM> struct Node;
template<int F, int REM, int E> struct Branch;

template<int F, int REM>
struct Node {
    static __device__ __forceinline__ void run(const float* xs, const float* w,
                                               int& t, float p,
                                               float& a0, float& a1) {
        Branch<F, REM, 0>::run(xs, w, t, p, a0, a1);
    }
};

// leaf: all 8 exponents assigned -> emit one term
template<int REM>
struct Node<NF, REM> {
    static __device__ __forceinline__ void run(const float* /*xs*/, const float* w,
                                               int& t, float p,
                                               float& a0, float& a1) {
        a0 = fmaf(w[t], p, a0);
        ++t;
    }
};

template<int F, int REM, int E>
struct Branch {
    static __device__ __forceinline__ void run(const float* xs, const float* w,
                                               int& t, float pf,
                                               float& a0, float& a1) {
        Node<F + 1, REM - E>::run(xs, w, t, pf, a0, a1);
        if constexpr (E < REM) {
            Branch<F, REM, E + 1>::run(xs, w, t, pf * xs[F], a1, a0);
        }
    }
};

__global__ __launch_bounds__(256)
void maclaurin_fused(const float* __restrict__ x,
                     const float* __restrict__ coefs,
                     const float* __restrict__ facs,
                     float* __restrict__ out, int n) {
    __shared__ __align__(16) float wl[NTERMS];

    const int tid = threadIdx.x;
    const int b   = blockIdx.x * blockDim.x + tid;

    // issue x loads first so their global latency hides under the LDS fill
    float xs[NF];
    if (b < n) {
        const float4* xp = (const float4*)(x + (size_t)b * NF);
        float4 v0 = xp[0];
        float4 v1 = xp[1];
        xs[0] = v0.x; xs[1] = v0.y; xs[2] = v0.z; xs[3] = v0.w;
        xs[4] = v1.x; xs[5] = v1.y; xs[6] = v1.z; xs[7] = v1.w;
    }

    // per-block w = coefs * facs into LDS (495 floats)
    if (tid < NTERMS)       wl[tid]       = coefs[tid]       * facs[tid];
    if (tid + 256 < NTERMS) wl[tid + 256] = coefs[tid + 256] * facs[tid + 256];
    __syncthreads();

    if (b >= n) return;

    float a0 = 0.0f, a1 = 0.0f;
    int t = 0;
    Node<0, DEG>::run(xs, wl, t, 1.0f, a0, a1);

    out[b] = a0 + a1;
}

// ---------------------------------------------------------------------------
// launch
// ---------------------------------------------------------------------------
extern "C" void kernel_launch(void* const* d_in, const int* in_sizes, int n_in,
                              void* d_out, int out_size, void* d_ws, size_t ws_size,
                              hipStream_t stream) {
    // inputs (setup_inputs order): x [B,8] f32, terms [495,8] f32,
    //                              coefs [1,495] f32, facs [495] f32
    const float* x     = (const float*)d_in[0];
    const float* coefs = (const float*)d_in[2];
    const float* facs  = (const float*)d_in[3];
    float* out = (float*)d_out;

    int n = in_sizes[0] / NF;    // 65536

    maclaurin_fused<<<(n + 255) / 256, 256, 0, stream>>>(x, coefs, facs, out, n);
}